// Round 6
// baseline (748.693 us; speedup 1.0000x reference)
//
#include <hip/hip_runtime.h>
#include <hip/hip_bf16.h>

// ---------------------------------------------------------------------------
// WindowAttention (Swin-style), MI355X / gfx950
//   x:(2048,49,512) f32 -> qkv GEMM (128^2, 2 blocks/CU, counted-vmcnt pipe)
//   -> attention (MFMA) -> proj GEMM -> out f32
// ---------------------------------------------------------------------------

typedef __bf16  bf16x8 __attribute__((ext_vector_type(8)));
typedef float   f32x4  __attribute__((ext_vector_type(4)));

#define B_TOT   2048
#define NTOK    49
#define CDIM    512
#define NHEAD   16
#define HDIM    32
#define MROWS   (B_TOT * NTOK)      // 100352
#define QKVN    (3 * CDIM)          // 1536

// ---- async global->LDS ------------------------------------------------------
__device__ __forceinline__ void load_lds16(const void* gptr, void* lptr) {
    __builtin_amdgcn_global_load_lds(
        (const __attribute__((address_space(1))) unsigned int*)gptr,
        (__attribute__((address_space(3))) unsigned int*)lptr,
        16, 0, 0);
}
__device__ __forceinline__ void load_lds4(const void* gptr, void* lptr) {
    __builtin_amdgcn_global_load_lds(
        (const __attribute__((address_space(1))) unsigned int*)gptr,
        (__attribute__((address_space(3))) unsigned int*)lptr,
        4, 0, 0);
}

// ---- fp32 -> bf16 convert (vectorized) -------------------------------------
__global__ void cvt_f32_bf16(const float* __restrict__ in,
                             __hip_bfloat16* __restrict__ out, int n4) {
    int idx = blockIdx.x * blockDim.x + threadIdx.x;
    int stride = gridDim.x * blockDim.x;
    for (int i = idx; i < n4; i += stride) {
        float4 f = ((const float4*)in)[i];
        union { __hip_bfloat16 h[4]; ushort4 u; } c;
        c.h[0] = __float2bfloat16(f.x);
        c.h[1] = __float2bfloat16(f.y);
        c.h[2] = __float2bfloat16(f.z);
        c.h[3] = __float2bfloat16(f.w);
        ((ushort4*)out)[i] = c.u;
    }
}

// ---------------------------------------------------------------------------
// 128x128 GEMM, 2 blocks/CU, C = A @ B^T + bias.
// A (M,K) bf16 rm, B (N,K) bf16 rm. M%128==0, N%128==0, K%64==0 (K=512).
// 4 waves (2x2 of 64x64), BK=64. LDS: A[2 slab][128 rows][128 B] = 32KB +
// B same = 64KB  => 2 blocks/CU (the point: a co-resident block fills this
// block's barrier/prologue/epilogue-drain bubbles; K=512 is too short to
// amortize them inside one block).
// Swizzle byte ^= ((row&7)<<4): zero bank conflicts (verified R3). Staging
// writes LINEAR LDS; global SOURCE is pre-inverse-swizzled.
// Per K-tile t (slab t&1), 2 phases:
//  ph1: read A mf0..3 x kk0,1 (8 b128) + B nf0,1 (4) ; STG_B(t+1) ;
//       BAR ; lgkm0 ; 16 MFMA ; BAR
//  ph2: read B nf2,3 (4) ; STG_A(t+2) [A-slab t&1 dead after ph1] ;
//       BAR ; lgkm0 ; 16 MFMA ; WAITV(4) ; BAR
// vmcnt ledger (4 loads per STG): prologue issues A0,B0,A1 (12), WAITV(4)
// retires tile0. Steady state at tile-t end: outstanding = A(t+1)[from t-1],
// B(t+1)[from t ph1], A(t+2)[from t ph2]; WAITV(4) retires exactly tile t+1,
// leaves A(t+2) in flight. Never drains to 0 mid-loop.
// ---------------------------------------------------------------------------
#define BARR    asm volatile("s_barrier" ::: "memory")
#define WAITV(N) asm volatile("s_waitcnt vmcnt(" #N ")" ::: "memory")
#define LGKM0   asm volatile("s_waitcnt lgkmcnt(0)" ::: "memory")
#define MFMA16(av, bv, cv) __builtin_amdgcn_mfma_f32_16x16x32_bf16(av, bv, cv, 0, 0, 0)

template <typename OutT>
__global__ __launch_bounds__(256, 2) void gemm128(
    const __hip_bfloat16* __restrict__ A,
    const __hip_bfloat16* __restrict__ B,
    const float* __restrict__ bias,
    OutT* __restrict__ C,
    int M, int N, int K, int nbx, int cpx)
{
    __shared__ __align__(16) char smem[65536];
    char* sA = smem;
    char* sB = smem + 32768;

    const int NT = K >> 6;           // 8

    const int tid  = threadIdx.x;
    const int lane = tid & 63;
    const int wave = tid >> 6;
    const int wm2  = wave >> 1;      // 0..1
    const int wn2  = wave & 1;       // 0..1
    const int l16  = lane & 15;
    const int quad = lane >> 4;

    // bijective XCD swizzle (gridDim %8==0), n-block fastest (A-panel L2 reuse)
    const int id = blockIdx.x;
    const int sw = (id & 7) * cpx + (id >> 3);
    const int mb = sw / nbx;
    const int nb = sw - mb * nbx;
    const int m0 = mb << 7;
    const int n0 = nb << 7;

    // ---- staging constants (inverse-swizzled global source) ----------------
    // LDS linear byte (within 16KB slab) = j*4096 + tid*16:
    //   row = j*32 + (tid>>3), swz col16 = tid&7; orig col16 = (tid&7)^(row&7)
    const int srow = tid >> 3;                                   // 0..31
    const int scg  = (((tid & 7) ^ (srow & 7)) << 3);            // elems
    const __hip_bfloat16* Asrc = A + (size_t)(m0 + srow) * K + scg;
    const __hip_bfloat16* Bsrc = B + (size_t)(n0 + srow) * K + scg;
    char* dA = sA + tid * 16;
    char* dB = sB + tid * 16;

#define STG_A(t2) { const int sl_ = ((t2) & 1) * 16384;                     \
    load_lds16(Asrc + (t2) * 64,                    dA + sl_);              \
    load_lds16(Asrc + (size_t)32 * K + (t2) * 64,   dA + sl_ + 4096);       \
    load_lds16(Asrc + (size_t)64 * K + (t2) * 64,   dA + sl_ + 8192);       \
    load_lds16(Asrc + (size_t)96 * K + (t2) * 64,   dA + sl_ + 12288); }
#define STG_B(t2) { const int sl_ = ((t2) & 1) * 16384;                     \
    load_lds16(Bsrc + (t2) * 64,                    dB + sl_);              \
    load_lds16(Bsrc + (size_t)32 * K + (t2) * 64,   dB + sl_ + 4096);       \
    load_lds16(Bsrc + (size_t)64 * K + (t2) * 64,   dB + sl_ + 8192);       \
    load_lds16(Bsrc + (size_t)96 * K + (t2) * 64,   dB + sl_ + 12288); }

    // prologue: A0,B0 (tile0), A1 ; retire tile0, keep A1 in flight
    STG_A(0); STG_B(0); STG_A(1);
    WAITV(4);
    BARR;

    // fragment addressing
    const int rbA = (wm2 * 64 + l16) * 128;   // byte row base in slab
    const int rbB = (wn2 * 64 + l16) * 128;
    const int c0 = (quad * 16) ^ ((l16 & 7) << 4);
    const int c1 = c0 ^ 64;

    bf16x8 ar[8], br[4], br2[4];
    f32x4 acc[4][4] = {};

#pragma unroll 2
    for (int t = 0; t < NT; ++t) {
        const int sl = (t & 1) * 16384;
        const char* pA = sA + sl + rbA;
        const char* pB = sB + sl + rbB;

        // ---- ph1: all A + B n-half 0 -----------------------------------
#pragma unroll
        for (int mf = 0; mf < 4; ++mf) {
            ar[2 * mf]     = *(const bf16x8*)(pA + mf * 2048 + c0);
            ar[2 * mf + 1] = *(const bf16x8*)(pA + mf * 2048 + c1);
        }
#pragma unroll
        for (int nf = 0; nf < 2; ++nf) {
            br[2 * nf]     = *(const bf16x8*)(pB + nf * 2048 + c0);
            br[2 * nf + 1] = *(const bf16x8*)(pB + nf * 2048 + c1);
        }
        if (t + 1 < NT) STG_B(t + 1);
        BARR; LGKM0;
        __builtin_amdgcn_s_setprio(1);
#pragma unroll
        for (int mf = 0; mf < 4; ++mf)
#pragma unroll
            for (int nf = 0; nf < 2; ++nf) {
                acc[mf][nf] = MFMA16(ar[2 * mf],     br[2 * nf],     acc[mf][nf]);
                acc[mf][nf] = MFMA16(ar[2 * mf + 1], br[2 * nf + 1], acc[mf][nf]);
            }
        __builtin_amdgcn_s_setprio(0);
        BARR;

        // ---- ph2: B n-half 1 (A-slab now dead -> stage A(t+2) into it) --
#pragma unroll
        for (int nf = 0; nf < 2; ++nf) {
            br2[2 * nf]     = *(const bf16x8*)(pB + (2 + nf) * 2048 + c0);
            br2[2 * nf + 1] = *(const bf16x8*)(pB + (2 + nf) * 2048 + c1);
        }
        if (t + 2 < NT) STG_A(t + 2);
        BARR; LGKM0;
        __builtin_amdgcn_s_setprio(1);
#pragma unroll
        for (int mf = 0; mf < 4; ++mf)
#pragma unroll
            for (int nf = 0; nf < 2; ++nf) {
                acc[mf][2 + nf] = MFMA16(ar[2 * mf],     br2[2 * nf],     acc[mf][2 + nf]);
                acc[mf][2 + nf] = MFMA16(ar[2 * mf + 1], br2[2 * nf + 1], acc[mf][2 + nf]);
            }
        __builtin_amdgcn_s_setprio(0);
        if (t + 2 < NT)      { WAITV(4); }   // tile t+1 landed; A(t+2) in flight
        else if (t + 1 < NT) { WAITV(0); }   // tail: last tile must land
        BARR;
    }
#undef STG_A
#undef STG_B

    // epilogue: D row = quad*4+r, col = l16 (verified layout)
#pragma unroll
    for (int mf = 0; mf < 4; ++mf) {
#pragma unroll
        for (int nf = 0; nf < 4; ++nf) {
            const int col = n0 + wn2 * 64 + nf * 16 + l16;
            const float bv = bias[col];
#pragma unroll
            for (int rr = 0; rr < 4; ++rr) {
                const int row = m0 + wm2 * 64 + mf * 16 + quad * 4 + rr;
                const float val = acc[mf][nf][rr] + bv;
                if constexpr (sizeof(OutT) == 2)
                    C[(size_t)row * N + col] = __float2bfloat16(val);
                else
                    C[(size_t)row * N + col] = val;
            }
        }
    }
}

// ---------------------------------------------------------------------------
// MFMA window attention. 1 block = 4 waves = heads hq*4..hq*4+3 of batch b.
// (unchanged)
// ---------------------------------------------------------------------------
#define QS_OFF   0
#define KS_OFF   12544
#define VS_OFF   25088
#define BIAS_OFF 41472
#define MASK_OFF 42824
#define SMEM_BYTES 52432

__global__ __launch_bounds__(256) void attn_mfma(
    const __hip_bfloat16* __restrict__ qkv,
    const float* __restrict__ mask,        // (64, 49, 49)
    const float* __restrict__ bias_table,  // (169, 16)
    __hip_bfloat16* __restrict__ out)
{
    __shared__ __align__(16) char smem[SMEM_BYTES];

    const int tid  = threadIdx.x;
    const int lane = tid & 63;
    const int w    = tid >> 6;
    const int l16  = lane & 15;
    const int quad = lane >> 4;
    const int b    = blockIdx.x >> 2;
    const int hq   = blockIdx.x & 3;

    {
        const long rowbase = (long)b * NTOK * QKVN;
        for (int e = tid; e < 2352; e += 256) {
            const int m   = e / 784;
            const int rr  = e - m * 784;
            const int tok = rr >> 4, seg = rr & 15;
            const int segl = seg ^ (tok & 7);
            const __hip_bfloat16* src =
                qkv + rowbase + (long)tok * QKVN + m * 512 + hq * 128 + segl * 8;
            load_lds16(src, smem + e * 16);
        }
        for (int e = tid; e < 960; e += 256)
            ((unsigned int*)(smem + VS_OFF + 49 * 256))[e] = 0u;
        const float* msrc = mask + (long)(b & 63) * (NTOK * NTOK);
        for (int e = tid; e < NTOK * NTOK; e += 256)
            load_lds4(msrc + e, smem + MASK_OFF + e * 4);
        __hip_bfloat16* sb = (__hip_bfloat16*)(smem + BIAS_OFF);
        for (int e = tid; e < 676; e += 256) {
            const int w2 = e / 169, rel = e - w2 * 169;
            sb[e] = __float2bfloat16(bias_table[rel * NHEAD + hq * 4 + w2]);
        }
    }
    __syncthreads();

    const int fro = (w * 64 + quad * 16) ^ ((l16 & 7) << 4);
    bf16x8 af[4], bf[4];
#pragma unroll
    for (int t = 0; t < 4; ++t) {
        const int tok = t * 16 + l16;
        af[t] = *(const bf16x8*)(smem + KS_OFF + tok * 256 + fro);
        bf[t] = *(const bf16x8*)(smem + QS_OFF + tok * 256 + fro);
    }
    f32x4 acc[4][4] = {};
#pragma unroll
    for (int i = 0; i < 4; ++i)
#pragma unroll
        for (int j = 0; j < 4; ++j)
            acc[i][j] = __builtin_amdgcn_mfma_f32_16x16x32_bf16(
                af[i], bf[j], acc[i][j], 0, 0, 0);
    __syncthreads();

    const float scale = 0.17677669529663687f;
    const float* smf = (const float*)(smem + MASK_OFF);
    const __hip_bfloat16* sb = (const __hip_bfloat16*)(smem + BIAS_OFF);
    const int quad4 = quad * 4;

    int kp[4][4];
#pragma unroll
    for (int i = 0; i < 4; ++i)
#pragma unroll
        for (int r = 0; r < 4; ++r) {
            const int k  = i * 16 + quad4 + r;
            const int rj = k / 7, cj = k - rj * 7;
            kp[i][r] = (6 - rj) * 13 + (6 - cj);
        }

    char* pbase = smem + w * 6272;
#pragma unroll
    for (int j = 0; j < 4; ++j) {
        const int q   = j * 16 + l16;
        const bool qok = q < NTOK;
        const int ri  = q / 7, ci = q - ri * 7;
        const int qp  = ri * 13 + ci;
        const int mrow = q * NTOK;
        float mx = -1e30f;
#pragma unroll
        for (int i = 0; i < 4; ++i)
#pragma unroll
            for (int r = 0; r < 4; ++r) {
                const int k = i * 16 + quad4 + r;
                float v;
                if (qok && k < NTOK) {
                    v = fmaf(acc[i][j][r], scale,
                             __bfloat162float(sb[w * 169 + qp + kp[i][r]]) + smf[mrow + k]);
                } else {
                    v = -1e30f;
                }
                acc[i][j][r] = v;
                mx = fmaxf(mx, v);
            }
        mx = fmaxf(mx, __shfl_xor(mx, 16));
        mx = fmaxf(mx, __shfl_xor(mx, 32));
        float s = 0.f;
#pragma unroll
        for (int i = 0; i < 4; ++i)
#pragma unroll
            for (int r = 0; r < 4; ++r) {
                const float ev = __expf(acc[i][j][r] - mx);
                acc[i][j][r] = ev;
                s += ev;
            }
        s += __shfl_xor(s, 16);
        s += __shfl_xor(s, 32);
        const float inv = 1.0f / s;
        if (qok) {
            char* prow = pbase + q * 128;
            const int xr = (q & 7) << 4;
#pragma unroll
            for (int i = 0; i < 4; ++i) {
                union { __hip_bfloat16 h[4]; uint2 u; } pk;
#pragma unroll
                for (int r = 0; r < 4; ++r)
                    pk.h[r] = __float2bfloat16(acc[i][j][r] * inv);
                *(uint2*)(prow + ((i * 32 + quad * 8) ^ xr)) = pk.u;
            }
        }
    }
    __syncthreads();

    bf16x8 pa[4][2];
#pragma unroll
    for (int mt = 0; mt < 4; ++mt) {
        const int q  = mt * 16 + l16;
        const int xr = (q & 7) << 4;
#pragma unroll
        for (int ks = 0; ks < 2; ++ks)
            pa[mt][ks] = *(const bf16x8*)(pbase + q * 128 + ((ks * 64 + quad * 16) ^ xr));
    }
    bf16x8 vb[2][2];
#pragma unroll
    for (int dt = 0; dt < 2; ++dt)
#pragma unroll
        for (int ks = 0; ks < 2; ++ks)
#pragma unroll
            for (int e = 0; e < 8; ++e) {
                const int key = ks * 32 + quad * 8 + e;
                const int dby = (w * 32 + dt * 16 + l16) * 2;
                vb[dt][ks][e] = *(const __bf16*)(smem + VS_OFF + key * 256 + (dby ^ (e << 4)));
            }
    f32x4 o[4][2] = {};
#pragma unroll
    for (int mt = 0; mt < 4; ++mt)
#pragma unroll
        for (int dt = 0; dt < 2; ++dt)
#pragma unroll
            for (int ks = 0; ks < 2; ++ks)
                o[mt][dt] = __builtin_amdgcn_mfma_f32_16x16x32_bf16(
                    pa[mt][ks], vb[dt][ks], o[mt][dt], 0, 0, 0);

    const long obase = (long)b * NTOK * CDIM + hq * 128 + w * 32;
#pragma unroll
    for (int mt = 0; mt < 4; ++mt)
#pragma unroll
        for (int r = 0; r < 4; ++r) {
            const int q = mt * 16 + quad4 + r;
            if (q < NTOK) {
                const long rb = obase + (long)q * CDIM;
#pragma unroll
                for (int dt = 0; dt < 2; ++dt)
                    out[rb + dt * 16 + l16] = __float2bfloat16(o[mt][dt][r]);
            }
        }
}

// ---------------------------------------------------------------------------
extern "C" void kernel_launch(void* const* d_in, const int* in_sizes, int n_in,
                              void* d_out, int out_size, void* d_ws, size_t ws_size,
                              hipStream_t stream) {
    const float* x          = (const float*)d_in[0];
    const float* mask       = (const float*)d_in[1];
    const float* qkv_w      = (const float*)d_in[2];
    const float* qkv_b      = (const float*)d_in[3];
    const float* proj_w     = (const float*)d_in[4];
    const float* proj_b     = (const float*)d_in[5];
    const float* bias_table = (const float*)d_in[6];

    char* ws = (char*)d_ws;
    __hip_bfloat16* xb   = (__hip_bfloat16*)(ws);
    __hip_bfloat16* qw   = (__hip_bfloat16*)(ws + 102760448);
    __hip_bfloat16* pw   = (__hip_bfloat16*)(ws + 104333312);
    __hip_bfloat16* qkvb = (__hip_bfloat16*)(ws + 104857600);
    __hip_bfloat16* ao   = xb;  // attn out reuses x_bf16 (GEMM1 done by then)

    cvt_f32_bf16<<<32768, 256, 0, stream>>>(x, xb, (MROWS * CDIM) / 4);
    cvt_f32_bf16<<<768,   256, 0, stream>>>(qkv_w, qw, (QKVN * CDIM) / 4);
    cvt_f32_bf16<<<256,   256, 0, stream>>>(proj_w, pw, (CDIM * CDIM) / 4);

    // qkv: M=100352, N=1536, K=512 -> 784*12 = 9408 blocks (%8==0)
    gemm128<__hip_bfloat16><<<9408, 256, 0, stream>>>(
        xb, qw, qkv_b, qkvb, MROWS, QKVN, CDIM, 12, 1176);

    attn_mfma<<<B_TOT * 4, 256, 0, stream>>>(qkvb, mask, bias_table, ao);

    // proj: M=100352, N=512, K=512 -> 784*4 = 3136 blocks (%8==0)
    gemm128<float><<<3136, 256, 0, stream>>>(
        ao, pw, proj_b, (float*)d_out, MROWS, CDIM, CDIM, 4, 392);
}